// Round 14
// baseline (312.743 us; speedup 1.0000x reference)
//
#include <hip/hip_runtime.h>

// ChildSumTreeLSTMCell — round 14: LDS diet -> 3 blocks/CU.
// R8 skeleton (32 nodes/block, 512 thr, in-register f-gates/c_tild, ct via
// global c-slot). Changes: wfs buffer moved to the global h-slot (dead until
// final epilogue; wave-private columns; barrier-drained before first read);
// Axh/Hm stored pad-free with T2 XOR swizzle (byte ^= (row&7)<<4).
// LDS 71168 -> 53248 B (= 13 x 4KB) => 3 blocks/CU, 3 barrier domains.

typedef __attribute__((ext_vector_type(8))) short short8;
typedef __attribute__((ext_vector_type(4))) float f32x4;
typedef __attribute__((ext_vector_type(4))) unsigned short us4;

#define NN 65536

__device__ __forceinline__ unsigned short f2bf(float f) {
  unsigned int u = __float_as_uint(f);
  u += 0x7FFFu + ((u >> 16) & 1u);   // RNE
  return (unsigned short)(u >> 16);
}
__device__ __forceinline__ float bf2f(unsigned short s) {
  return __uint_as_float(((unsigned int)s) << 16);
}
__device__ __forceinline__ f32x4 mfma16(short8 a, short8 b, f32x4 c) {
  return __builtin_amdgcn_mfma_f32_16x16x32_bf16(a, b, c, 0, 0, 0);
}
__device__ __forceinline__ float sigmoidf_(float v) { return 1.0f / (1.0f + __expf(-v)); }
__device__ __forceinline__ float ftanh(float v) { return 1.0f - 2.0f / (__expf(2.0f * v) + 1.0f); }

// ---------------- weight prep ----------------
// frag layout: [kt][ct][lane][8]; lane holds B[k=kt*32+8*(lane>>4)+j][col=ct*16+(lane&15)]
__global__ void prep_all(const float* __restrict__ Wf, const float* __restrict__ Uf,
                         const float* __restrict__ Wiou, const float* __restrict__ Uiou,
                         unsigned short* __restrict__ ws) {
  int idx = blockIdx.x * 256 + threadIdx.x;          // 589824 total
  if (idx < 81920) {                                  // Bwf [10][16][64][8]
    int j = idx & 7, lane = (idx >> 3) & 63, ct = (idx >> 9) & 15, kt = idx >> 13;
    int k = kt*32 + ((lane >> 4) << 3) + j, col = ct*16 + (lane & 15);
    ws[idx] = f2bf(k < 300 ? Wf[col*300 + k] : 0.0f);
  } else if (idx < 147456) {                          // Buf [8][16][64][8]
    int i = idx - 81920;
    int j = i & 7, lane = (i >> 3) & 63, ct = (i >> 9) & 15, kt = i >> 13;
    int k = kt*32 + ((lane >> 4) << 3) + j, col = ct*16 + (lane & 15);
    ws[idx] = f2bf(Uf[col*256 + k]);
  } else {                                            // Biou [18][48][64][8]; ct = cb*3+gate
    int i = idx - 147456;
    int j = i & 7, lane = (i >> 3) & 63;
    int rest = i >> 9, ct = rest % 48, kt = rest / 48;
    int k = kt*32 + ((lane >> 4) << 3) + j;
    int g = (ct % 3)*256 + (ct/3)*16 + (lane & 15);
    float v = (k < 320) ? (k < 300 ? Wiou[g*300 + k] : 0.0f) : Uiou[g*256 + (k - 320)];
    ws[idx] = f2bf(v);
  }
}

// ---------------- fused cell ----------------
__global__ __launch_bounds__(512, 4) void fused_cell(
    const float* __restrict__ x, const float* __restrict__ h_msgs,
    const float* __restrict__ c_msgs,
    const float* __restrict__ b_iou, const float* __restrict__ b_Uiou,
    const float* __restrict__ bWf, const float* __restrict__ bUf,
    const unsigned short* __restrict__ Bwf, const unsigned short* __restrict__ Buf,
    const unsigned short* __restrict__ Biou,
    float* __restrict__ out_h, float* __restrict__ out_c) {
  __shared__ alignas(16) char smem[53248];
  // Axh: rows 0..31, 576 ushorts (1152 B) each, XOR-swizzled, bytes [0, 36864)
  // Hm : rows 0..31, 256 ushorts (512 B)  each, XOR-swizzled, bytes [36864, 53248)
  unsigned int* IUOp = (unsigned int*)(smem + 36864);   // [32][128] overlays Hm

  const int tid = threadIdx.x;
  const int n0 = blockIdx.x * 32;
  const int wave = tid >> 6, lane = tid & 63;
  const int lrow = lane & 15, lgrp = lane >> 4;
  const int nl = wave;                 // wave owns node nl of each 8-node chunk
  const f32x4 fz = {0.0f, 0.0f, 0.0f, 0.0f};

  auto axp = [&](int row, int colB) -> char* {          // Axh swizzled byte addr
    return smem + ((row*1152 + colB) ^ ((row & 7) << 4));
  };
  auto hmp = [&](int row, int colB) -> char* {          // Hm swizzled byte addr
    return smem + 36864 + ((row*512 + colB) ^ ((row & 7) << 4));
  };

  f32x4 hvN[4];                        // in-flight h_msgs for NEXT chunk

  auto issue_h = [&](int chunk) {
    int node = n0 + chunk*8 + nl;
    const float* hp = h_msgs + (size_t)node*1024 + lane*4;
#pragma unroll
    for (int k = 0; k < 4; ++k) hvN[k] = *(const f32x4*)(hp + k*256);
  };

  auto write_h = [&](int chunk) {      // regs -> Hm + h_tild -> Axh
    f32x4 s = fz;
#pragma unroll
    for (int k = 0; k < 4; ++k) {
      us4 o;
#pragma unroll
      for (int e = 0; e < 4; ++e) { s[e] += hvN[k][e]; o[e] = f2bf(hvN[k][e]); }
      *(us4*)hmp(nl*4 + k, lane*8) = o;
    }
    us4 ht;
#pragma unroll
    for (int e = 0; e < 4; ++e) ht[e] = f2bf(s[e]);
    *(us4*)axp(chunk*8 + nl, 640 + lane*8) = ht;
  };

  auto uh_gemm = [&](f32x4 a2[2][2]) {
    const unsigned short* bp = Buf + ((wave*2)*64 + lane)*8;
    short8 b0 = *(const short8*)bp;
    short8 b1 = *(const short8*)(bp + 512);
#pragma unroll
    for (int ks = 0; ks < 8; ++ks) {
      short8 nb0 = b0, nb1 = b1;
      if (ks < 7) {
        const unsigned short* np = Buf + (((ks+1)*16 + wave*2)*64 + lane)*8;
        nb0 = *(const short8*)np;
        nb1 = *(const short8*)(np + 512);
      }
#pragma unroll
      for (int rt = 0; rt < 2; ++rt) {
        short8 a = *(const short8*)hmp(rt*16 + lrow, ks*64 + lgrp*16);
        a2[rt][0] = mfma16(a, b0, a2[rt][0]);
        a2[rt][1] = mfma16(a, b1, a2[rt][1]);
      }
      b0 = nb0; b1 = nb1;
    }
  };

  // ---- prologue: issue h0, stage x (swizzled), write Hm0, issue h1
  issue_h(0);
  for (int i = tid; i < 32*80; i += 512) {
    int r = i / 80, c4 = i - r*80;
    f32x4 v = fz;
    if (c4 < 75) v = *(const f32x4*)&x[(size_t)(n0 + r)*300 + c4*4];
    us4 o;
#pragma unroll
    for (int e = 0; e < 4; ++e) o[e] = f2bf(v[e]);
    *(us4*)axp(r, c4*8) = o;
  }
  write_h(0);
  issue_h(1);
  __syncthreads();                     // B1: Axh-x + Hm0 ready

  // ---- wf GEMM: [32 x 320] x [320 x 256] -> global h-slot (f32, +bias)
  {
    const unsigned short* bp = Bwf + ((wave*2)*64 + lane)*8;
    short8 b0 = *(const short8*)bp;
    short8 b1 = *(const short8*)(bp + 512);
    f32x4 w00 = fz, w01 = fz, w10 = fz, w11 = fz;
#pragma unroll
    for (int ks = 0; ks < 10; ++ks) {
      short8 nb0 = b0, nb1 = b1;
      if (ks < 9) {
        const unsigned short* np = Bwf + (((ks+1)*16 + wave*2)*64 + lane)*8;
        nb0 = *(const short8*)np;
        nb1 = *(const short8*)(np + 512);
      }
      short8 a0 = *(const short8*)axp(lrow, ks*64 + lgrp*16);
      short8 a1 = *(const short8*)axp(16 + lrow, ks*64 + lgrp*16);
      w00 = mfma16(a0, b0, w00); w10 = mfma16(a1, b0, w10);
      w01 = mfma16(a0, b1, w01); w11 = mfma16(a1, b1, w11);
      b0 = nb0; b1 = nb1;
    }
#pragma unroll
    for (int ct = 0; ct < 2; ++ct) {
      int col = wave*32 + ct*16 + lrow;
      float bias = bWf[col];
      f32x4 v0 = ct ? w01 : w00, v1 = ct ? w11 : w10;
#pragma unroll
      for (int r = 0; r < 4; ++r) {
        out_h[(size_t)(n0 + lgrp*4 + r)*256 + col]      = v0[r] + bias;
        out_h[(size_t)(n0 + 16 + lgrp*4 + r)*256 + col] = v1[r] + bias;
      }
    }
  }
  __syncthreads();                     // B2: wf stores drained -> readable

  float bu[2];
  bu[0] = bUf[wave*32 + lrow];
  bu[1] = bUf[wave*32 + 16 + lrow];

  // ---- 4 chunks: uh GEMM + fully in-register f-gates/c_tild
#pragma unroll
  for (int chunk = 0; chunk < 4; ++chunk) {
    float cm[2][2][4];
    float wfv[2][2];
#pragma unroll
    for (int rt = 0; rt < 2; ++rt) {
      int node = chunk*8 + rt*4 + lgrp;
      const float* cp = c_msgs + (size_t)(n0 + node)*1024 + wave*32 + lrow;
#pragma unroll
      for (int ct2 = 0; ct2 < 2; ++ct2) {
        wfv[rt][ct2] = out_h[(size_t)(n0 + node)*256 + wave*32 + ct2*16 + lrow];
#pragma unroll
        for (int r = 0; r < 4; ++r) cm[rt][ct2][r] = cp[r*256 + ct2*16];
      }
    }

    f32x4 a2[2][2] = {{fz, fz}, {fz, fz}};
    uh_gemm(a2);

    // lane holds uh for node rt*4+lgrp, all 4 children, col wave*32+ct2*16+lrow
#pragma unroll
    for (int rt = 0; rt < 2; ++rt) {
      int node = chunk*8 + rt*4 + lgrp;
#pragma unroll
      for (int ct2 = 0; ct2 < 2; ++ct2) {
        int col = wave*32 + ct2*16 + lrow;
        float s = 0.0f;
#pragma unroll
        for (int r = 0; r < 4; ++r) {
          float fg = sigmoidf_(a2[rt][ct2][r] + wfv[rt][ct2] + bu[ct2]);
          s += fg * cm[rt][ct2][r];
        }
        out_c[(size_t)(n0 + node)*256 + col] = s;   // c_tild, read back later
      }
    }
    __syncthreads();                   // all uh reads of Hm(chunk) done
    if (chunk < 3) {
      write_h(chunk + 1);
      if (chunk < 2) issue_h(chunk + 2);
      __syncthreads();                 // Hm(next) ready
    }
  }
  // last barrier also separates final Hm reads from IUOp overlay

  // ---- iou GEMM: [32 x 576] x [576 x 768]; pass p covers cols p*128..+127
#pragma unroll 1
  for (int p = 0; p < 2; ++p) {
    int cb = p*8 + wave;               // col-block in [0,16)
    int ct0 = cb*3;
    int col = cb*16 + lrow;
    f32x4 aI0 = fz, aO0 = fz, aU0 = fz, aI1 = fz, aO1 = fz, aU1 = fz;
    const unsigned short* bp = Biou + ((size_t)ct0*64 + lane)*8;
    short8 bi = *(const short8*)bp;
    short8 bo = *(const short8*)(bp + 512);
    short8 bu8 = *(const short8*)(bp + 1024);
#pragma unroll
    for (int ks = 0; ks < 18; ++ks) {
      short8 ni = bi, no = bo, nu = bu8;
      if (ks < 17) {
        const unsigned short* np = Biou + ((size_t)((ks+1)*48 + ct0)*64 + lane)*8;
        ni = *(const short8*)np;
        no = *(const short8*)(np + 512);
        nu = *(const short8*)(np + 1024);
      }
      short8 a0 = *(const short8*)axp(lrow, ks*64 + lgrp*16);
      short8 a1 = *(const short8*)axp(16 + lrow, ks*64 + lgrp*16);
      aI0 = mfma16(a0, bi, aI0);  aI1 = mfma16(a1, bi, aI1);
      aO0 = mfma16(a0, bo, aO0);  aO1 = mfma16(a1, bo, aO1);
      aU0 = mfma16(a0, bu8, aU0); aU1 = mfma16(a1, bu8, aU1);
      bi = ni; bo = no; bu8 = nu;
    }
    float bI = b_iou[col]       + b_Uiou[col];
    float bO = b_iou[256 + col] + b_Uiou[256 + col];
    float bU = b_iou[512 + col] + b_Uiou[512 + col];
#pragma unroll
    for (int rt = 0; rt < 2; ++rt) {
      f32x4 ai = rt ? aI1 : aI0, ao = rt ? aO1 : aO0, au = rt ? aU1 : aU0;
#pragma unroll
      for (int r = 0; r < 4; ++r) {
        float iv = sigmoidf_(ai[r] + bI);
        float ov = sigmoidf_(ao[r] + bO);
        float uv = ftanh(au[r] + bU);
        IUOp[(rt*16 + lgrp*4 + r)*128 + wave*16 + lrow] =
            (unsigned int)f2bf(iv * uv) | ((unsigned int)f2bf(ov) << 16);
      }
    }
    __syncthreads();                   // IUOp(pass p) visible

    // epilogue: 32 nodes x 128 contiguous cols, fully coalesced
#pragma unroll
    for (int e = 0; e < 8; ++e) {
      int idx = e*512 + tid;
      int node = idx >> 7, slot = idx & 127;
      unsigned int pk = IUOp[node*128 + slot];
      size_t base = (size_t)(n0 + node)*256 + p*128 + slot;
      float iu = bf2f((unsigned short)(pk & 0xFFFFu));
      float ov = bf2f((unsigned short)(pk >> 16));
      float c  = iu + out_c[base];     // c_tild (barrier-separated)
      out_c[base] = c;
      out_h[base] = ov * ftanh(c);
    }
    if (p == 0) __syncthreads();       // IUOp reads done before pass-1 writes
  }
}

extern "C" void kernel_launch(void* const* d_in, const int* in_sizes, int n_in,
                              void* d_out, int out_size, void* d_ws, size_t ws_size,
                              hipStream_t stream) {
  const float* x      = (const float*)d_in[0];
  const float* h_msgs = (const float*)d_in[1];
  const float* c_msgs = (const float*)d_in[2];
  const float* W_iou  = (const float*)d_in[3];
  const float* b_iou  = (const float*)d_in[4];
  const float* U_iou  = (const float*)d_in[5];
  const float* b_Uiou = (const float*)d_in[6];
  const float* W_f    = (const float*)d_in[7];
  const float* b_Wf   = (const float*)d_in[8];
  const float* U_f    = (const float*)d_in[9];
  const float* b_Uf   = (const float*)d_in[10];

  unsigned short* ws   = (unsigned short*)d_ws;
  unsigned short* Bwf  = ws;                    // [10][16][64][8]
  unsigned short* Buf  = ws + 81920;            // [8][16][64][8]
  unsigned short* Biou = ws + 147456;           // [18][48][64][8]

  float* h_slot = (float*)d_out;                // wf staging, then h
  float* c_slot = h_slot + (size_t)NN*256;      // c_tild, then c

  prep_all<<<2304, 256, 0, stream>>>(W_f, U_f, W_iou, U_iou, ws);
  fused_cell<<<NN/32, 512, 0, stream>>>(x, h_msgs, c_msgs, b_iou, b_Uiou,
                                        b_Wf, b_Uf, Bwf, Buf, Biou, h_slot, c_slot);
}

// Round 15
// 266.049 us; speedup vs baseline: 1.1755x; 1.1755x over previous
//
#include <hip/hip_runtime.h>

// ChildSumTreeLSTMCell — round 15: R8 base + register-neutral stall removal.
// Lesson bank: unified VGPR sits just under the 128/16-wave boundary — any
// structural change adding ~8+ arch regs halves occupancy (R9-R12). So: R8
// skeleton untouched; changes are (1) dual-pass IUO buffer -> ONE barrier +
// ONE merged epilogue (was 2 barriers + 2 epilogues), (2) epilogue batches
// all ctl/IUO loads up front (transient regs only), (3) wfs reads hoisted.

typedef __attribute__((ext_vector_type(8))) short short8;
typedef __attribute__((ext_vector_type(4))) float f32x4;
typedef __attribute__((ext_vector_type(4))) unsigned short us4;
typedef __attribute__((ext_vector_type(4))) unsigned int u32x4;

#define NN 65536

__device__ __forceinline__ unsigned short f2bf(float f) {
  unsigned int u = __float_as_uint(f);
  u += 0x7FFFu + ((u >> 16) & 1u);   // RNE
  return (unsigned short)(u >> 16);
}
__device__ __forceinline__ float bf2f(unsigned short s) {
  return __uint_as_float(((unsigned int)s) << 16);
}
__device__ __forceinline__ f32x4 mfma16(short8 a, short8 b, f32x4 c) {
  return __builtin_amdgcn_mfma_f32_16x16x32_bf16(a, b, c, 0, 0, 0);
}
__device__ __forceinline__ float sigmoidf_(float v) { return 1.0f / (1.0f + __expf(-v)); }
__device__ __forceinline__ float ftanh(float v) { return 1.0f - 2.0f / (__expf(2.0f * v) + 1.0f); }

// ---------------- weight prep ----------------
// frag layout: [kt][ct][lane][8]; lane holds B[k=kt*32+8*(lane>>4)+j][col=ct*16+(lane&15)]
__global__ void prep_all(const float* __restrict__ Wf, const float* __restrict__ Uf,
                         const float* __restrict__ Wiou, const float* __restrict__ Uiou,
                         unsigned short* __restrict__ ws) {
  int idx = blockIdx.x * 256 + threadIdx.x;          // 589824 total
  if (idx < 81920) {                                  // Bwf [10][16][64][8]
    int j = idx & 7, lane = (idx >> 3) & 63, ct = (idx >> 9) & 15, kt = idx >> 13;
    int k = kt*32 + ((lane >> 4) << 3) + j, col = ct*16 + (lane & 15);
    ws[idx] = f2bf(k < 300 ? Wf[col*300 + k] : 0.0f);
  } else if (idx < 147456) {                          // Buf [8][16][64][8]
    int i = idx - 81920;
    int j = i & 7, lane = (i >> 3) & 63, ct = (i >> 9) & 15, kt = i >> 13;
    int k = kt*32 + ((lane >> 4) << 3) + j, col = ct*16 + (lane & 15);
    ws[idx] = f2bf(Uf[col*256 + k]);
  } else {                                            // Biou [18][48][64][8]; ct = cb*3+gate
    int i = idx - 147456;
    int j = i & 7, lane = (i >> 3) & 63;
    int rest = i >> 9, ct = rest % 48, kt = rest / 48;
    int k = kt*32 + ((lane >> 4) << 3) + j;
    int g = (ct % 3)*256 + (ct/3)*16 + (lane & 15);
    float v = (k < 320) ? (k < 300 ? Wiou[g*300 + k] : 0.0f) : Uiou[g*256 + (k - 320)];
    ws[idx] = f2bf(v);
  }
}

// ---------------- fused cell ----------------
__global__ __launch_bounds__(512, 4) void fused_cell(
    const float* __restrict__ x, const float* __restrict__ h_msgs,
    const float* __restrict__ c_msgs,
    const float* __restrict__ b_iou, const float* __restrict__ b_Uiou,
    const float* __restrict__ bWf, const float* __restrict__ bUf,
    const unsigned short* __restrict__ Bwf, const unsigned short* __restrict__ Buf,
    const unsigned short* __restrict__ Biou,
    float* __restrict__ out_h, float* __restrict__ out_c) {
  __shared__ alignas(16) char smem[71168];
  unsigned short* Axh = (unsigned short*)smem;            // [32][584]  37376 B
  unsigned short* Hm  = (unsigned short*)(smem + 37376);  // [32][264]  16896 B
  unsigned short* wfs = (unsigned short*)(smem + 54272);  // [32][264]  16896 B
  unsigned int*   IUO = (unsigned int*)(smem + 37376);    // [32][260]  33280 B overlay (both passes)

  const int tid = threadIdx.x;
  const int n0 = blockIdx.x * 32;
  const int wave = tid >> 6, lane = tid & 63;
  const int lrow = lane & 15, lgrp = lane >> 4;
  const int nl = wave;                 // wave owns node nl of each 8-node chunk
  const f32x4 fz = {0.0f, 0.0f, 0.0f, 0.0f};

  f32x4 hvN[4];                        // in-flight h_msgs for NEXT chunk

  auto issue_h = [&](int chunk) {      // global -> regs (issue only)
    int node = n0 + chunk*8 + nl;
    const float* hp = h_msgs + (size_t)node*1024 + lane*4;
#pragma unroll
    for (int k = 0; k < 4; ++k) hvN[k] = *(const f32x4*)(hp + k*256);
  };

  auto write_h = [&](int chunk) {      // regs -> Hm + h_tild -> Axh
    f32x4 s = fz;
#pragma unroll
    for (int k = 0; k < 4; ++k) {
      us4 o;
#pragma unroll
      for (int e = 0; e < 4; ++e) { s[e] += hvN[k][e]; o[e] = f2bf(hvN[k][e]); }
      *(us4*)&Hm[(nl*4 + k)*264 + lane*4] = o;
    }
    us4 ht;
#pragma unroll
    for (int e = 0; e < 4; ++e) ht[e] = f2bf(s[e]);
    *(us4*)&Axh[(chunk*8 + nl)*584 + 320 + lane*4] = ht;
  };

  auto uh_gemm = [&](f32x4 a2[2][2]) {
    const unsigned short* bp = Buf + ((wave*2)*64 + lane)*8;
    short8 b0 = *(const short8*)bp;
    short8 b1 = *(const short8*)(bp + 512);
#pragma unroll
    for (int ks = 0; ks < 8; ++ks) {
      short8 nb0 = b0, nb1 = b1;
      if (ks < 7) {
        const unsigned short* np = Buf + (((ks+1)*16 + wave*2)*64 + lane)*8;
        nb0 = *(const short8*)np;
        nb1 = *(const short8*)(np + 512);
      }
#pragma unroll
      for (int rt = 0; rt < 2; ++rt) {
        short8 a = *(const short8*)&Hm[(rt*16 + lrow)*264 + ks*32 + lgrp*8];
        a2[rt][0] = mfma16(a, b0, a2[rt][0]);
        a2[rt][1] = mfma16(a, b1, a2[rt][1]);
      }
      b0 = nb0; b1 = nb1;
    }
  };

  // ---- prologue: issue h0, stage x, write Hm0, issue h1
  issue_h(0);
  for (int i = tid; i < 32*80; i += 512) {
    int r = i / 80, c4 = i - r*80;
    f32x4 v = fz;
    if (c4 < 75) v = *(const f32x4*)&x[(size_t)(n0 + r)*300 + c4*4];
    us4 o;
#pragma unroll
    for (int e = 0; e < 4; ++e) o[e] = f2bf(v[e]);
    *(us4*)&Axh[r*584 + c4*4] = o;
  }
  write_h(0);
  issue_h(1);
  __syncthreads();                     // Axh(x) + Hm0 ready

  // ---- wf GEMM: [32 x 320] x [320 x 256] -> wfs (bf16, +bias), wave-private cols
  {
    const unsigned short* bp = Bwf + ((wave*2)*64 + lane)*8;
    short8 b0 = *(const short8*)bp;
    short8 b1 = *(const short8*)(bp + 512);
    f32x4 w00 = fz, w01 = fz, w10 = fz, w11 = fz;
#pragma unroll
    for (int ks = 0; ks < 10; ++ks) {
      short8 nb0 = b0, nb1 = b1;
      if (ks < 9) {
        const unsigned short* np = Bwf + (((ks+1)*16 + wave*2)*64 + lane)*8;
        nb0 = *(const short8*)np;
        nb1 = *(const short8*)(np + 512);
      }
      short8 a0 = *(const short8*)&Axh[lrow*584 + ks*32 + lgrp*8];
      short8 a1 = *(const short8*)&Axh[(16 + lrow)*584 + ks*32 + lgrp*8];
      w00 = mfma16(a0, b0, w00); w10 = mfma16(a1, b0, w10);
      w01 = mfma16(a0, b1, w01); w11 = mfma16(a1, b1, w11);
      b0 = nb0; b1 = nb1;
    }
#pragma unroll
    for (int ct = 0; ct < 2; ++ct) {
      int col = wave*32 + ct*16 + lrow;
      float bias = bWf[col];
      f32x4 v0 = ct ? w01 : w00, v1 = ct ? w11 : w10;
#pragma unroll
      for (int r = 0; r < 4; ++r) {
        wfs[(lgrp*4 + r)*264 + col]      = f2bf(v0[r] + bias);
        wfs[(16 + lgrp*4 + r)*264 + col] = f2bf(v1[r] + bias);
      }
    }
  }
  __syncthreads();                     // wfs visible before chunk0 f-epilogue

  float bu[2];
  bu[0] = bUf[wave*32 + lrow];
  bu[1] = bUf[wave*32 + 16 + lrow];

  // ---- 4 chunks: uh GEMM + fully in-register f-gates/c_tild
#pragma unroll
  for (int chunk = 0; chunk < 4; ++chunk) {
    // issue c_msgs + hoist wfs reads (LDS) before the GEMM
    float cm[2][2][4];
    float wfv[2][2];
#pragma unroll
    for (int rt = 0; rt < 2; ++rt) {
      int node = chunk*8 + rt*4 + lgrp;
      const float* cp = c_msgs + (size_t)(n0 + node)*1024 + wave*32 + lrow;
#pragma unroll
      for (int ct2 = 0; ct2 < 2; ++ct2) {
        wfv[rt][ct2] = bf2f(wfs[node*264 + wave*32 + ct2*16 + lrow]);
#pragma unroll
        for (int r = 0; r < 4; ++r) cm[rt][ct2][r] = cp[r*256 + ct2*16];
      }
    }

    f32x4 a2[2][2] = {{fz, fz}, {fz, fz}};
    uh_gemm(a2);

    // lane holds uh for node rt*4+lgrp, all 4 children, col wave*32+ct2*16+lrow
#pragma unroll
    for (int rt = 0; rt < 2; ++rt) {
      int node = chunk*8 + rt*4 + lgrp;
#pragma unroll
      for (int ct2 = 0; ct2 < 2; ++ct2) {
        int col = wave*32 + ct2*16 + lrow;
        float s = 0.0f;
#pragma unroll
        for (int r = 0; r < 4; ++r) {
          float fg = sigmoidf_(a2[rt][ct2][r] + wfv[rt][ct2] + bu[ct2]);
          s += fg * cm[rt][ct2][r];
        }
        out_c[(size_t)(n0 + node)*256 + col] = s;   // c_tild, read back at the end
      }
    }
    __syncthreads();                   // all uh reads of Hm(chunk) done
    if (chunk < 3) {
      write_h(chunk + 1);
      if (chunk < 2) issue_h(chunk + 2);
      __syncthreads();                 // Hm(next) ready
    }
  }
  // post-chunk barrier also separates last Hm/wfs reads from IUO overlay

  // ---- iou GEMM: [32 x 576] x [576 x 768]; 2 passes, both write IUO (disjoint cols)
#pragma unroll 1
  for (int p = 0; p < 2; ++p) {
    int cb = wave*2 + p;               // col-block in [0,16)
    int ct0 = cb*3;
    int col = cb*16 + lrow;
    f32x4 aI0 = fz, aO0 = fz, aU0 = fz, aI1 = fz, aO1 = fz, aU1 = fz;
    const unsigned short* bp = Biou + ((size_t)ct0*64 + lane)*8;
    short8 bi = *(const short8*)bp;
    short8 bo = *(const short8*)(bp + 512);
    short8 bu8 = *(const short8*)(bp + 1024);
#pragma unroll
    for (int ks = 0; ks < 18; ++ks) {
      short8 ni = bi, no = bo, nu = bu8;
      if (ks < 17) {
        const unsigned short* np = Biou + ((size_t)((ks+1)*48 + ct0)*64 + lane)*8;
        ni = *(const short8*)np;
        no = *(const short8*)(np + 512);
        nu = *(const short8*)(np + 1024);
      }
      short8 a0 = *(const short8*)&Axh[lrow*584 + ks*32 + lgrp*8];
      short8 a1 = *(const short8*)&Axh[(16 + lrow)*584 + ks*32 + lgrp*8];
      aI0 = mfma16(a0, bi, aI0);  aI1 = mfma16(a1, bi, aI1);
      aO0 = mfma16(a0, bo, aO0);  aO1 = mfma16(a1, bo, aO1);
      aU0 = mfma16(a0, bu8, aU0); aU1 = mfma16(a1, bu8, aU1);
      bi = ni; bo = no; bu8 = nu;
    }
    float bI = b_iou[col]       + b_Uiou[col];
    float bO = b_iou[256 + col] + b_Uiou[256 + col];
    float bU = b_iou[512 + col] + b_Uiou[512 + col];
#pragma unroll
    for (int rt = 0; rt < 2; ++rt) {
      f32x4 ai = rt ? aI1 : aI0, ao = rt ? aO1 : aO0, au = rt ? aU1 : aU0;
#pragma unroll
      for (int r = 0; r < 4; ++r) {
        float iv = sigmoidf_(ai[r] + bI);
        float ov = sigmoidf_(ao[r] + bO);
        float uv = ftanh(au[r] + bU);
        IUO[(rt*16 + lgrp*4 + r)*260 + col] =
            (unsigned int)f2bf(iv * uv) | ((unsigned int)f2bf(ov) << 16);
      }
    }
  }
  __syncthreads();                     // both passes' IUO visible

  // ---- merged final epilogue: batch-issue all ctl + IUO loads, then compute
  {
    f32x4 ctl[4];
    u32x4 pk[4];
#pragma unroll
    for (int chunk = 0; chunk < 4; ++chunk) {
      int nb = chunk*8 + nl;
      ctl[chunk] = *(const f32x4*)&out_c[(size_t)(n0 + nb)*256 + lane*4];
      pk[chunk]  = *(const u32x4*)&IUO[nb*260 + lane*4];
    }
#pragma unroll
    for (int chunk = 0; chunk < 4; ++chunk) {
      int nb = chunk*8 + nl;
      size_t base = (size_t)(n0 + nb)*256 + lane*4;
      f32x4 hv, cvo;
#pragma unroll
      for (int e = 0; e < 4; ++e) {
        float iu = bf2f((unsigned short)(pk[chunk][e] & 0xFFFFu));
        float ov = bf2f((unsigned short)(pk[chunk][e] >> 16));
        float c  = iu + ctl[chunk][e];
        cvo[e] = c;
        hv[e] = ov * ftanh(c);
      }
      *(f32x4*)&out_h[base] = hv;
      *(f32x4*)&out_c[base] = cvo;
    }
  }
}

extern "C" void kernel_launch(void* const* d_in, const int* in_sizes, int n_in,
                              void* d_out, int out_size, void* d_ws, size_t ws_size,
                              hipStream_t stream) {
  const float* x      = (const float*)d_in[0];
  const float* h_msgs = (const float*)d_in[1];
  const float* c_msgs = (const float*)d_in[2];
  const float* W_iou  = (const float*)d_in[3];
  const float* b_iou  = (const float*)d_in[4];
  const float* U_iou  = (const float*)d_in[5];
  const float* b_Uiou = (const float*)d_in[6];
  const float* W_f    = (const float*)d_in[7];
  const float* b_Wf   = (const float*)d_in[8];
  const float* U_f    = (const float*)d_in[9];
  const float* b_Uf   = (const float*)d_in[10];

  unsigned short* ws   = (unsigned short*)d_ws;
  unsigned short* Bwf  = ws;                    // [10][16][64][8]
  unsigned short* Buf  = ws + 81920;            // [8][16][64][8]
  unsigned short* Biou = ws + 147456;           // [18][48][64][8]

  float* h_slot = (float*)d_out;
  float* c_slot = h_slot + (size_t)NN*256;

  prep_all<<<2304, 256, 0, stream>>>(W_f, U_f, W_iou, U_iou, ws);
  fused_cell<<<NN/32, 512, 0, stream>>>(x, h_msgs, c_msgs, b_iou, b_Uiou,
                                        b_Wf, b_Uf, Bwf, Buf, Biou, h_slot, c_slot);
}